// Round 1
// baseline (1681.070 us; speedup 1.0000x reference)
//
#include <hip/hip_runtime.h>
#include <hip/hip_bf16.h>

// CrossAttention: q/k/v = in + dw3x3(pw1x1(in)); transposed attention per head
// (32x32 gram over n=36864); out = proj1x1(attn @ v).
// Decomposition:
//   K1 x3 : fused pw(96x96 per-pixel matvec) + depthwise 3x3 + residual
//            -> q,k as bf16 (gram-only consumers), v as f32
//   K2    : row L2 norms of q,k (normalization folded into gram post-scale)
//   K3    : raw gram partials over 6 n-chunks (deterministic, no atomics)
//   K4    : normalize + softmax + M[b] = proj @ attn_blockdiag  (96x96/batch)
//   K5    : out[b,o,p] = sum_g M[b,o,g] * v[b,g,p]   (attn-apply + proj fused)

#define B_  8
#define C_  96
#define HH  192
#define WW  192
#define HW_ (HH*WW)      // 36864
#define HC_ 32
#define TS  16           // tile side
#define HS  18           // halo side
#define HP  20           // padded halo row (even, 4B-aligned rows)

__device__ __forceinline__ unsigned short f2b(float f){
  unsigned u = __float_as_uint(f);
  u += 0x7fffu + ((u >> 16) & 1u);
  return (unsigned short)(u >> 16);
}
__device__ __forceinline__ float blo(unsigned u){ return __uint_as_float(u << 16); }
__device__ __forceinline__ float bhi(unsigned u){ return __uint_as_float(u & 0xffff0000u); }

__device__ __forceinline__ float dot8(uint4 a, uint4 b, float s){
  s = fmaf(blo(a.x), blo(b.x), s); s = fmaf(bhi(a.x), bhi(b.x), s);
  s = fmaf(blo(a.y), blo(b.y), s); s = fmaf(bhi(a.y), bhi(b.y), s);
  s = fmaf(blo(a.z), blo(b.z), s); s = fmaf(bhi(a.z), bhi(b.z), s);
  s = fmaf(blo(a.w), blo(b.w), s); s = fmaf(bhi(a.w), bhi(b.w), s);
  return s;
}

// ---------------- K1: fused pointwise + depthwise + residual ----------------
// grid (12,12,8), block 384. Tile 16x16, halo 18x18=324 (threads 324..383 idle
// in phase 1). Weights read wave-uniformly -> scalar loads (no LDS).
template<int VOUT>  // 0: bf16 out (q,k), 1: f32 out (v)
__global__ __launch_bounds__(384, 3)
void k_qkv(const float* __restrict__ in, const float* __restrict__ pw,
           const float* __restrict__ dwt, void* __restrict__ outp)
{
  __shared__ unsigned short h_s[C_][HS*HP];   // bf16 h over halo, 69.1 KB

  const int t  = threadIdx.x;
  const int b  = blockIdx.z;
  const int ty0 = blockIdx.y * TS, tx0 = blockIdx.x * TS;

  // ---- phase 1: h[c, halo] = pw @ x[:, halo]
  {
    const int hy = t / HS, hx = t - hy * HS;       // valid for t<324
    const int gy = ty0 + hy - 1, gx = tx0 + hx - 1;
    const bool inimg = (t < HS*HS) && (gy >= 0) && (gy < HH) && (gx >= 0) && (gx < WW);
    float xreg[C_];
    const float* px = in + (size_t)b * C_ * HW_ + (size_t)gy * WW + gx;
    #pragma unroll
    for (int j = 0; j < C_; j++) xreg[j] = inimg ? px[(size_t)j * HW_] : 0.f;

    const int pix = hy * HP + hx;
    #pragma unroll 1
    for (int c8 = 0; c8 < C_; c8 += 8){
      float a[8];
      #pragma unroll
      for (int k = 0; k < 8; k++) a[k] = 0.f;
      #pragma unroll
      for (int j = 0; j < C_; j++){
        const float xj = xreg[j];
        #pragma unroll
        for (int k = 0; k < 8; k++)
          a[k] = fmaf(pw[(c8 + k) * C_ + j], xj, a[k]);   // uniform -> s_load
      }
      if (t < HS*HS){
        #pragma unroll
        for (int k = 0; k < 8; k++) h_s[c8 + k][pix] = f2b(a[k]);
      }
    }
  }
  __syncthreads();

  // ---- phase 2: depthwise 3x3 + residual; task = (c, tile-row), 1536 tasks
  #pragma unroll 1
  for (int task = t; task < C_ * TS; task += 384){
    const int c  = task >> 4;
    const int ty = task & 15;
    const int gy = ty0 + ty;
    float w[9];
    #pragma unroll
    for (int i = 0; i < 9; i++) w[i] = dwt[c * 9 + i];    // uniform-ish scalar
    float acc[TS];
    const float* xr = in + ((size_t)b * C_ + c) * HW_ + (size_t)gy * WW + tx0;
    #pragma unroll
    for (int i = 0; i < TS; i++) acc[i] = xr[i];          // residual
    #pragma unroll
    for (int dy = 0; dy < 3; dy++){
      const unsigned* rp = (const unsigned*)&h_s[c][(ty + dy) * HP];
      float v[HS];
      #pragma unroll
      for (int i = 0; i < 9; i++){
        unsigned u = rp[i];
        v[2*i]   = blo(u);
        v[2*i+1] = bhi(u);
      }
      #pragma unroll
      for (int dx = 0; dx < 3; dx++){
        const float wv = w[dy * 3 + dx];
        #pragma unroll
        for (int i = 0; i < TS; i++) acc[i] = fmaf(wv, v[i + dx], acc[i]);
      }
    }
    const size_t o = ((size_t)b * C_ + c) * HW_ + (size_t)gy * WW + tx0;
    if (VOUT){
      float4* op = (float4*)((float*)outp + o);           // 64B-aligned (tx0%16==0)
      #pragma unroll
      for (int i = 0; i < 4; i++)
        op[i] = make_float4(acc[4*i], acc[4*i+1], acc[4*i+2], acc[4*i+3]);
    } else {
      uint4* op = (uint4*)((unsigned short*)outp + o);    // 32B-aligned
      unsigned pk[8];
      #pragma unroll
      for (int i = 0; i < 8; i++)
        pk[i] = (unsigned)f2b(acc[2*i]) | ((unsigned)f2b(acc[2*i+1]) << 16);
      op[0] = make_uint4(pk[0], pk[1], pk[2], pk[3]);
      op[1] = make_uint4(pk[4], pk[5], pk[6], pk[7]);
    }
  }
}

// ---------------- K2: row sum-of-squares for q,k ----------------
__global__ __launch_bounds__(256)
void k_norm(const unsigned short* __restrict__ qb, const unsigned short* __restrict__ kb,
            float* __restrict__ qq, float* __restrict__ kk)
{
  const int c = blockIdx.x, b = blockIdx.y;
  const unsigned short* base = (blockIdx.z == 0 ? qb : kb) + ((size_t)b * C_ + c) * HW_;
  const uint4* p = (const uint4*)base;
  float s = 0.f;
  for (int i = threadIdx.x; i < HW_/8; i += 256){
    uint4 u = p[i];
    s = dot8(u, u, s);
  }
  #pragma unroll
  for (int off = 32; off; off >>= 1) s += __shfl_xor(s, off);
  __shared__ float r[4];
  if ((threadIdx.x & 63) == 0) r[threadIdx.x >> 6] = s;
  __syncthreads();
  if (threadIdx.x == 0)
    (blockIdx.z == 0 ? qq : kk)[b * C_ + c] = r[0] + r[1] + r[2] + r[3];
}

// ---------------- K3: raw gram partials ----------------
// grid (4 c-split, 6 n-split, 24 bh), block 256 = 8c x 32d. No atomics.
__global__ __launch_bounds__(256)
void k_gram(const unsigned short* __restrict__ qb, const unsigned short* __restrict__ kb,
            float* __restrict__ Gp)
{
  const int d  = threadIdx.x & 31, cl = threadIdx.x >> 5;
  const int c  = blockIdx.x * 8 + cl;
  const int ns = blockIdx.y;
  const int bh = blockIdx.z, b = bh / 3, h = bh - b * 3;
  const uint4* qr = (const uint4*)(qb + ((size_t)b * C_ + h * HC_ + c) * HW_) + ns * 768;
  const uint4* kr = (const uint4*)(kb + ((size_t)b * C_ + h * HC_ + d) * HW_) + ns * 768;
  float a0 = 0.f, a1 = 0.f;
  #pragma unroll 2
  for (int i = 0; i < 768; i += 2){
    a0 = dot8(qr[i],   kr[i],   a0);
    a1 = dot8(qr[i+1], kr[i+1], a1);
  }
  Gp[(((size_t)ns * 24 + bh) * HC_ + c) * HC_ + d] = a0 + a1;
}

// ---------------- K4: normalize + softmax + M = proj @ attn_bd ----------------
__global__ __launch_bounds__(256)
void k_attn(const float* __restrict__ Gp, const float* __restrict__ qq,
            const float* __restrict__ kk, const float* __restrict__ temp,
            const float* __restrict__ proj, float* __restrict__ M)
{
  const int b = blockIdx.x, t = threadIdx.x;
  __shared__ float at[3][HC_][HC_];
  for (int idx = t; idx < 3 * HC_ * HC_; idx += 256){
    const int h = idx >> 10, rem = idx & 1023, cc = rem >> 5, dd = rem & 31;
    float g = 0.f;
    #pragma unroll
    for (int ns = 0; ns < 6; ns++)
      g += Gp[(((size_t)ns * 24 + b * 3 + h) * HC_ + cc) * HC_ + dd];
    const float nq = fmaxf(sqrtf(qq[b * C_ + h * HC_ + cc]), 1e-12f);
    const float nk = fmaxf(sqrtf(kk[b * C_ + h * HC_ + dd]), 1e-12f);
    at[h][cc][dd] = g / (nq * nk) * temp[h];
  }
  __syncthreads();
  if (t < C_){
    const int h = t >> 5, cc = t & 31;
    float m = -1e30f;
    for (int dd = 0; dd < HC_; dd++) m = fmaxf(m, at[h][cc][dd]);
    float s = 0.f;
    for (int dd = 0; dd < HC_; dd++){ float e = expf(at[h][cc][dd] - m); at[h][cc][dd] = e; s += e; }
    const float inv = 1.f / s;
    for (int dd = 0; dd < HC_; dd++) at[h][cc][dd] *= inv;
  }
  __syncthreads();
  for (int idx = t; idx < C_ * C_; idx += 256){
    const int o = idx / 96, hd = idx - o * 96, h = hd >> 5, dd = hd & 31;
    float m = 0.f;
    #pragma unroll
    for (int cc = 0; cc < HC_; cc++)
      m = fmaf(proj[o * C_ + h * HC_ + cc], at[h][cc][dd], m);
    M[(size_t)b * C_ * C_ + idx] = m;
  }
}

// ---------------- K5: out = M[b] @ v (fused attn-apply + proj) ----------------
__global__ __launch_bounds__(256, 3)
void k_out(const float* __restrict__ vf, const float* __restrict__ M,
           float* __restrict__ out)
{
  const int p = blockIdx.x * 256 + threadIdx.x;
  const int b = blockIdx.y;
  const float* vb = vf + (size_t)b * C_ * HW_ + p;
  float vreg[C_];
  #pragma unroll
  for (int g = 0; g < C_; g++) vreg[g] = vb[(size_t)g * HW_];
  const float* Mb = M + (size_t)b * C_ * C_;
  float* ob = out + (size_t)b * C_ * HW_ + p;
  #pragma unroll 1
  for (int o4 = 0; o4 < C_; o4 += 4){
    float a0 = 0.f, a1 = 0.f, a2 = 0.f, a3 = 0.f;
    #pragma unroll
    for (int g = 0; g < C_; g++){
      const float vg = vreg[g];
      a0 = fmaf(Mb[(o4+0) * C_ + g], vg, a0);   // uniform -> s_load
      a1 = fmaf(Mb[(o4+1) * C_ + g], vg, a1);
      a2 = fmaf(Mb[(o4+2) * C_ + g], vg, a2);
      a3 = fmaf(Mb[(o4+3) * C_ + g], vg, a3);
    }
    ob[(size_t)(o4+0) * HW_] = a0;
    ob[(size_t)(o4+1) * HW_] = a1;
    ob[(size_t)(o4+2) * HW_] = a2;
    ob[(size_t)(o4+3) * HW_] = a3;
  }
}

extern "C" void kernel_launch(void* const* d_in, const int* in_sizes, int n_in,
                              void* d_out, int out_size, void* d_ws, size_t ws_size,
                              hipStream_t stream)
{
  const float* x    = (const float*)d_in[0];
  const float* y    = (const float*)d_in[1];
  const float* z    = (const float*)d_in[2];
  const float* temp = (const float*)d_in[3];
  const float* q_pw = (const float*)d_in[4];
  const float* q_dw = (const float*)d_in[5];
  const float* k_pw = (const float*)d_in[6];
  const float* k_dw = (const float*)d_in[7];
  const float* v_pw = (const float*)d_in[8];
  const float* v_dw = (const float*)d_in[9];
  const float* proj = (const float*)d_in[10];

  // workspace layout (bytes), all 16B-aligned; total ~227.4 MB
  char* ws = (char*)d_ws;
  unsigned short* qb = (unsigned short*)(ws);                  // 56,623,104
  unsigned short* kb = (unsigned short*)(ws + 56623104);       // 56,623,104
  float* vf = (float*)(ws + 113246208);                        // 113,246,208
  float* qq = (float*)(ws + 226492416);                        // 3,072
  float* kk = (float*)(ws + 226495488);                        // 3,072
  float* Gp = (float*)(ws + 226498560);                        // 589,824
  float* M  = (float*)(ws + 227088384);                        // 294,912
  float* out = (float*)d_out;

  const dim3 g1(12, 12, B_);
  k_qkv<0><<<g1, 384, 0, stream>>>(x, q_pw, q_dw, qb);
  k_qkv<0><<<g1, 384, 0, stream>>>(y, k_pw, k_dw, kb);
  k_qkv<1><<<g1, 384, 0, stream>>>(z, v_pw, v_dw, vf);
  k_norm<<<dim3(C_, B_, 2), 256, 0, stream>>>(qb, kb, qq, kk);
  k_gram<<<dim3(4, 6, B_ * 3), 256, 0, stream>>>(qb, kb, Gp);
  k_attn<<<B_, 256, 0, stream>>>(Gp, qq, kk, temp, proj, M);
  k_out<<<dim3(HW_ / 256, B_), 256, 0, stream>>>(vf, M, out);
}